// Round 1
// baseline (900.769 us; speedup 1.0000x reference)
//
#include <hip/hip_runtime.h>

// Depthwise 3x3 conv, channel-multiplier 2, shared single-channel kernel.
// x: [B=16, H=224, W=224, C=96] f32 NHWC
// k: [3,3,1,2] f32   bias: [192] f32
// out[b,y,x, 2c+m] = sum_{dy,dx} x[b, y+dy-1, x+dx-1, c] * k[dy,dx,0,m] + bias[2c+m]
// (jax conv_general_dilated = cross-correlation, no kernel flip; SAME pad = 1 each side)

#define BATCH 16
#define H 224
#define W 224
#define C 96
#define CG (C / 4)        // 24 float4 channel-groups
#define CO (C * 2)        // 192 output channels
#define XT 8              // x positions per block

__global__ __launch_bounds__(CG * XT) void dwconv_kernel(
    const float* __restrict__ x,
    const float* __restrict__ k,
    const float* __restrict__ bias,
    float* __restrict__ out)
{
    const int cg = threadIdx.x;                    // 0..23 channel group
    const int xo = blockIdx.x * XT + threadIdx.y;  // 0..223
    const int y  = blockIdx.y;
    const int b  = blockIdx.z;

    // 18 weights; uniform address -> scalar loads, broadcast from cache
    float w[3][3][2];
#pragma unroll
    for (int dy = 0; dy < 3; ++dy)
#pragma unroll
        for (int dx = 0; dx < 3; ++dx)
#pragma unroll
            for (int m = 0; m < 2; ++m)
                w[dy][dx][m] = k[(dy * 3 + dx) * 2 + m];

    // accA = out channels 8cg+0..3 = (c0m0, c0m1, c1m0, c1m1)
    // accB = out channels 8cg+4..7 = (c2m0, c2m1, c3m0, c3m1)
    float4 accA = make_float4(0.f, 0.f, 0.f, 0.f);
    float4 accB = make_float4(0.f, 0.f, 0.f, 0.f);

    const float* xb = x + ((size_t)b * H * W) * C + (size_t)cg * 4;

    const bool interior = (y >= 1) & (y <= H - 2) & (xo >= 1) & (xo <= W - 2);

    if (interior) {
#pragma unroll
        for (int dy = 0; dy < 3; ++dy) {
            const float* row = xb + ((size_t)(y + dy - 1) * W + (xo - 1)) * C;
#pragma unroll
            for (int dx = 0; dx < 3; ++dx) {
                const float4 v = *(const float4*)(row + (size_t)dx * C);
                const float w0 = w[dy][dx][0], w1 = w[dy][dx][1];
                accA.x += v.x * w0;  accA.y += v.x * w1;
                accA.z += v.y * w0;  accA.w += v.y * w1;
                accB.x += v.z * w0;  accB.y += v.z * w1;
                accB.z += v.w * w0;  accB.w += v.w * w1;
            }
        }
    } else {
#pragma unroll
        for (int dy = 0; dy < 3; ++dy) {
            const int yy = y + dy - 1;
            if (yy < 0 || yy >= H) continue;
#pragma unroll
            for (int dx = 0; dx < 3; ++dx) {
                const int xx = xo + dx - 1;
                if (xx < 0 || xx >= W) continue;
                const float4 v = *(const float4*)(xb + ((size_t)yy * W + xx) * C);
                const float w0 = w[dy][dx][0], w1 = w[dy][dx][1];
                accA.x += v.x * w0;  accA.y += v.x * w1;
                accA.z += v.y * w0;  accA.w += v.y * w1;
                accB.x += v.z * w0;  accB.y += v.z * w1;
                accB.z += v.w * w0;  accB.w += v.w * w1;
            }
        }
    }

    // bias: out channels 8cg .. 8cg+7 -> two float4s
    const float4 bA = ((const float4*)bias)[2 * cg + 0];
    const float4 bB = ((const float4*)bias)[2 * cg + 1];
    accA.x += bA.x; accA.y += bA.y; accA.z += bA.z; accA.w += bA.w;
    accB.x += bB.x; accB.y += bB.y; accB.z += bB.z; accB.w += bB.w;

    float4* o = (float4*)(out + (((size_t)b * H + y) * W + xo) * CO + (size_t)cg * 8);
    o[0] = accA;
    o[1] = accB;
}

extern "C" void kernel_launch(void* const* d_in, const int* in_sizes, int n_in,
                              void* d_out, int out_size, void* d_ws, size_t ws_size,
                              hipStream_t stream) {
    const float* x    = (const float*)d_in[0];
    const float* k    = (const float*)d_in[1];
    const float* bias = (const float*)d_in[2];
    float* out = (float*)d_out;

    dim3 block(CG, XT, 1);             // 192 threads = 3 waves
    dim3 grid(W / XT, H, BATCH);       // 28 x 224 x 16
    hipLaunchKernelGGL(dwconv_kernel, grid, block, 0, stream, x, k, bias, out);
}